// Round 4
// baseline (5940.126 us; speedup 1.0000x reference)
//
#include <hip/hip_runtime.h>

// LSTM: N=256, L=2048, IN=8, H1=256, H2=128, OUT=1
// 128 WGs = 16 batch-groups x 8 unit-slices; weights persistent in registers.
// Cross-WG h-exchange: self-validating tagged u64 packet words ([h1|h0|tag16]),
// fire-and-forget relaxed agent stores, per-word tag-equality polling.
// One LLC round-trip per step; 2 barriers per step; no fences, no flags.

typedef __attribute__((ext_vector_type(8))) short short8;
typedef __attribute__((ext_vector_type(4))) float f32x4;
typedef __attribute__((ext_vector_type(2))) float f32x2;

#define LSEQ 2048

__device__ __forceinline__ unsigned short f2bf(float f) {
  unsigned int u = __float_as_uint(f);
  return (unsigned short)((u + 0x7FFFu + ((u >> 16) & 1u)) >> 16);
}
__device__ __forceinline__ float sigm(float x) {
  float e = __builtin_amdgcn_exp2f(-1.44269504089f * x);
  return __builtin_amdgcn_rcpf(1.0f + e);
}
__device__ __forceinline__ float tanh_(float x) {
  float ax = __builtin_fabsf(x);
  float e = __builtin_amdgcn_exp2f(-2.88539008178f * ax);
  float t = (1.0f - e) * __builtin_amdgcn_rcpf(1.0f + e);
  return __builtin_copysignf(t, x);
}
// raw barrier: LDS ordering only -- no vmcnt drain (HBM stores stay async)
__device__ __forceinline__ void wg_barrier() {
  __asm__ __volatile__("s_waitcnt lgkmcnt(0)" ::: "memory");
  __builtin_amdgcn_s_barrier();
}

// ---------------- setup: swizzle weights + ZERO packet tags (replay safety) ----------------
__global__ void prep_kernel(const float* __restrict__ W_ih, const float* __restrict__ W_hh,
                            const float* __restrict__ b_ih, const float* __restrict__ b_hh,
                            const float* __restrict__ W1,
                            unsigned short* __restrict__ wstream,
                            unsigned short* __restrict__ w1stream,
                            float* __restrict__ bias,
                            unsigned long long* __restrict__ packets) {
  int tid = blockIdx.x * 256 + threadIdx.x;
  if (tid < 36864) {                      // 576 gate fragments * 64 lanes
    int f = tid >> 6, l = tid & 63;
    int w = f / 72, rem = f % 72, nt = rem / 9, kt = rem % 9;
    int g = (nt >> 1) * 256 + w * 32 + (nt & 1) * 16 + (l & 15);
    int k0 = kt * 32 + (l >> 4) * 8;
    unsigned short* dst = wstream + (size_t)f * 512 + l * 8;
#pragma unroll
    for (int j = 0; j < 8; j++) {
      int k = k0 + j;
      float v;
      if (k < 256)       v = W_hh[g * 256 + k];
      else if (k < 264)  v = W_ih[g * 9 + (k - 256)];   // x columns
      else               v = 0.0f;                       // prev handled rank-1
      dst[j] = f2bf(v);
    }
  } else if (tid < 36864 + 4096) {        // 64 W1 fragments
    int t2 = tid - 36864;
    int f = t2 >> 6, l = t2 & 63;
    int w = f >> 3, kt = f & 7;
    int h2 = w * 16 + (l & 15);
    int k0 = kt * 32 + (l >> 4) * 8;
    unsigned short* dst = w1stream + (size_t)f * 512 + l * 8;
#pragma unroll
    for (int j = 0; j < 8; j++) dst[j] = f2bf(W1[h2 * 256 + k0 + j]);
  } else if (tid < 36864 + 4096 + 1024) {
    int g = tid - 36864 - 4096;
    bias[g] = b_ih[g] + b_hh[g];
  } else if (tid < 36864 + 4096 + 1024 + 65536) {
    packets[tid - 41984] = 0ull;          // tag=0 never matches k>=1
  }
}

// ---------------- main: 128 WGs x 512 threads ----------------
__global__ __launch_bounds__(512, 2) void lstm_main(
    const float* __restrict__ x, const float* __restrict__ W_ih,
    const float* __restrict__ b1, const float* __restrict__ W2, const float* __restrict__ b2,
    const unsigned short* __restrict__ wstream, const unsigned short* __restrict__ w1stream,
    const float* __restrict__ bias,
    unsigned long long* __restrict__ packets,
    float* __restrict__ out0, float* __restrict__ out1) {
  __shared__ unsigned short A[2][16][296];   // [slot][sample][K]: 0..255 h, 256..263 x, 264.. zero
  __shared__ float gbuf[4][16][34];          // [gate][sample][unit]
  __shared__ float part[8][17];              // MLP partials [wave][sample]

  const int tid = threadIdx.x;
  const int w = tid >> 6, l = tid & 63, lr = l & 15, lg = l >> 4;
  const int bg = blockIdx.x & 15, sl = blockIdx.x >> 4;
  const int n0 = bg * 16, u0 = sl * 32;

  // persistent weights in registers (17 frags = 68 VGPRs)
  short8 wg_[9], w1_[8];
  {
    const short8* wp = (const short8*)wstream;
    const short8* w1p = (const short8*)w1stream;
#pragma unroll
    for (int kt = 0; kt < 9; kt++) wg_[kt] = wp[(size_t)((sl * 8 + w) * 9 + kt) * 64 + l];
#pragma unroll
    for (int kt = 0; kt < 8; kt++) w1_[kt] = w1p[(size_t)(w * 8 + kt) * 64 + l];
  }
  const float biasv = bias[(w >> 1) * 256 + u0 + (w & 1) * 16 + lr];
  const float b1v = b1[w * 16 + lr];
  const float w2v = W2[w * 16 + lr];
  const float b2v = b2[0];

  // cell lanes: waves 0..3 (tid<256): sample cs, unit pair u0+cu2, u0+cu2+1
  const int cs = tid >> 4, cu2 = (tid & 15) * 2;
  float wpv[8];
  float c0r = 0.f, c1r = 0.f;
  if (tid < 256) {
#pragma unroll
    for (int g = 0; g < 4; g++) {
      wpv[g * 2 + 0] = W_ih[(g * 256 + u0 + cu2) * 9 + 8];
      wpv[g * 2 + 1] = W_ih[(g * 256 + u0 + cu2 + 1) * 9 + 8];
    }
  }

  for (int i = tid; i < 2 * 16 * 296; i += 512) ((unsigned short*)A)[i] = 0;

  // x prefetch for k=0 (wave sl, lanes 0..31: sample l>>1, half l&1)
  f32x4 xv = {0.f, 0.f, 0.f, 0.f};
  if (w == sl && l < 32)
    xv = *(const f32x4*)(x + (size_t)(n0 + (l >> 1)) * LSEQ * 8 + (l & 1) * 4);

  __syncthreads();

  for (int k = 0; k <= LSEQ; k++) {
    const int slot = k & 1;

    // ---- P1: stage x (wave sl) / receive tagged h-words (other waves) ----
    if (w == sl) {
      if (l < 32 && k < LSEQ) {
        unsigned long long xp = (unsigned long long)f2bf(xv.x)
                              | ((unsigned long long)f2bf(xv.y) << 16)
                              | ((unsigned long long)f2bf(xv.z) << 32)
                              | ((unsigned long long)f2bf(xv.w) << 48);
        *(unsigned long long*)&A[slot][l >> 1][256 + (l & 1) * 4] = xp;
        if (k + 1 < LSEQ)
          xv = *(const f32x4*)(x + ((size_t)(n0 + (l >> 1)) * LSEQ + (k + 1)) * 8 + (l & 1) * 4);
      }
    } else if (k > 0) {
      const unsigned long long* pk = packets + (((size_t)slot * 16 + bg) * 8 + w) * 256 + l * 4;
      unsigned long long v[4];
#pragma unroll
      for (int i = 0; i < 4; i++)          // optimistic batch: 4 loads in flight
        v[i] = __hip_atomic_load(&pk[i], __ATOMIC_RELAXED, __HIP_MEMORY_SCOPE_AGENT);
#pragma unroll
      for (int i = 0; i < 4; i++)
        while ((unsigned)(v[i] & 0xFFFFu) != (unsigned)k)
          v[i] = __hip_atomic_load(&pk[i], __ATOMIC_RELAXED, __HIP_MEMORY_SCOPE_AGENT);
#pragma unroll
      for (int i = 0; i < 4; i++) {
        int W = l * 4 + i, s = W >> 4, pr = W & 15;
        *(unsigned int*)&A[slot][s][w * 32 + pr * 2] = (unsigned int)(v[i] >> 16);
      }
    }
    wg_barrier();   // B1: A[slot] complete (h_{k-1} + x_k)

    // ---- P2: gate GEMM (k<LSEQ) + MLP for out_{k-1} (k>0), shared A-fragments ----
    short8 afr[9];
#pragma unroll
    for (int kt = 0; kt < 9; kt++)
      afr[kt] = *(const short8*)&A[slot][lr][kt * 32 + lg * 8];
    if (k < LSEQ) {
      f32x4 acc = {biasv, biasv, biasv, biasv};
#pragma unroll
      for (int kt = 0; kt < 9; kt++)
        acc = __builtin_amdgcn_mfma_f32_16x16x32_bf16(afr[kt], wg_[kt], acc, 0, 0, 0);
#pragma unroll
      for (int r = 0; r < 4; r++) gbuf[w >> 1][lg * 4 + r][(w & 1) * 16 + lr] = acc[r];
    }
    if (k > 0) {
      f32x4 m = {b1v, b1v, b1v, b1v};
#pragma unroll
      for (int kt = 0; kt < 8; kt++)
        m = __builtin_amdgcn_mfma_f32_16x16x32_bf16(afr[kt], w1_[kt], m, 0, 0, 0);
      float p[4];
#pragma unroll
      for (int r = 0; r < 4; r++) {
        float v = m[r] > 0.f ? m[r] : 0.f;
        p[r] = v * w2v;
        p[r] += __shfl_xor(p[r], 1, 64);
        p[r] += __shfl_xor(p[r], 2, 64);
        p[r] += __shfl_xor(p[r], 4, 64);
        p[r] += __shfl_xor(p[r], 8, 64);
      }
      if (lr == 0) {
#pragma unroll
        for (int r = 0; r < 4; r++) part[w][lg * 4 + r] = p[r];
      }
    }
    wg_barrier();   // B2: gbuf + part ready

    // ---- P3 (waves 0..3): out reduce + cell update + tagged publish ----
    if (tid < 256) {
      float o = 0.f;
      if (k > 0) {
        o = b2v;
#pragma unroll
        for (int i = 0; i < 8; i++) o += part[i][cs];
        if (cu2 == 0 && sl == 0)
          __builtin_nontemporal_store(o, out0 + (size_t)(n0 + cs) * LSEQ + (k - 1));
      }
      if (k < LSEQ) {
        float gi0 = gbuf[0][cs][cu2] + wpv[0] * o, gi1 = gbuf[0][cs][cu2 + 1] + wpv[1] * o;
        float gf0 = gbuf[1][cs][cu2] + wpv[2] * o, gf1 = gbuf[1][cs][cu2 + 1] + wpv[3] * o;
        float gg0 = gbuf[2][cs][cu2] + wpv[4] * o, gg1 = gbuf[2][cs][cu2 + 1] + wpv[5] * o;
        float go0 = gbuf[3][cs][cu2] + wpv[6] * o, go1 = gbuf[3][cs][cu2 + 1] + wpv[7] * o;
        c0r = sigm(gf0) * c0r + sigm(gi0) * tanh_(gg0);
        c1r = sigm(gf1) * c1r + sigm(gi1) * tanh_(gg1);
        float h0 = sigm(go0) * tanh_(c0r);
        float h1 = sigm(go1) * tanh_(c1r);
        f32x2 cv = {c0r, c1r};
        __builtin_nontemporal_store(cv,
            (f32x2*)(out1 + ((size_t)(n0 + cs) * LSEQ + k) * 256 + u0 + cu2));
        unsigned int hb0 = f2bf(h0), hb1 = f2bf(h1);
        // fire-and-forget tagged word: [h1|h0|tag=k+1]
        unsigned long long wv = (unsigned long long)(unsigned)(k + 1)
                              | ((unsigned long long)hb0 << 16)
                              | ((unsigned long long)hb1 << 32);
        unsigned long long* dst =
            packets + (((size_t)((k + 1) & 1) * 16 + bg) * 8 + sl) * 256 + tid;
        __hip_atomic_store(dst, wv, __ATOMIC_RELAXED, __HIP_MEMORY_SCOPE_AGENT);
        // own-slice short circuit into next A slot
        *(unsigned int*)&A[slot ^ 1][cs][u0 + cu2] = hb0 | (hb1 << 16);
      }
    }
    // no barrier: P3 LDS reads precede (program order) each wave's next P1;
    // gbuf/part next written only after B1(k+1); A[slot^1] regions disjoint.
  }
}

extern "C" void kernel_launch(void* const* d_in, const int* in_sizes, int n_in,
                              void* d_out, int out_size, void* d_ws, size_t ws_size,
                              hipStream_t stream) {
  const float* x    = (const float*)d_in[0];
  const float* W_ih = (const float*)d_in[1];
  const float* W_hh = (const float*)d_in[2];
  const float* b_ih = (const float*)d_in[3];
  const float* b_hh = (const float*)d_in[4];
  const float* W1   = (const float*)d_in[5];
  const float* b1   = (const float*)d_in[6];
  const float* W2   = (const float*)d_in[7];
  const float* b2   = (const float*)d_in[8];

  unsigned short*     wstream  = (unsigned short*)d_ws;                      // 1,179,648 B
  unsigned short*     w1stream = (unsigned short*)((char*)d_ws + 1179648);   // 65,536 B
  float*              bias     = (float*)((char*)d_ws + 1179648 + 65536);    // 4,096 B
  unsigned long long* packets  = (unsigned long long*)((char*)d_ws + 1249280); // 2*16*8*256*8 = 524,288 B

  float* out0 = (float*)d_out;            // [256,2048,1]
  float* out1 = out0 + 256 * LSEQ;        // [256,2048,256]

  prep_kernel<<<420, 256, 0, stream>>>(W_ih, W_hh, b_ih, b_hh, W1, wstream, w1stream, bias, packets);
  lstm_main<<<128, 512, 0, stream>>>(x, W_ih, b1, W2, b2, wstream, w1stream, bias, packets,
                                     out0, out1);
}